// Round 16
// baseline (101.022 us; speedup 1.0000x reference)
//
#include <hip/hip_runtime.h>

#define D_ 64
#define R_ 50
#define N_ 20001
#define A_ 6
#define E_ 30000
#define B_ 4
#define C_ 500
#define FEAT_ 128
#define SC_CAP 8192
#define DCAP 32
#define NLIST_CAP 16384
#define EPSB 32

__device__ __forceinline__ float rlane(float v, int k) {
  return __builtin_bit_cast(float, __builtin_amdgcn_readlane(__builtin_bit_cast(int, v), k));
}
__device__ __forceinline__ float wave_sum(float v) {
#pragma unroll
  for (int off = 32; off; off >>= 1) v += __shfl_xor(v, off);
  return v;
}
__device__ __forceinline__ float sel6(float p0, float p1, float p2, float p3,
                                      float p4, float p5, int a) {
  float r = p0;
  r = (a == 1) ? p1 : r; r = (a == 2) ? p2 : r; r = (a == 3) ? p3 : r;
  r = (a == 4) ? p4 : r; r = (a == 5) ? p5 : r;
  return r;
}

// ---------- K1: zero scratch (deg/dirtyA/dirty_n/ctrs/eflag/emap/cflag) ----------

#define ZQUADS 42509  // 680144 bytes / 16

__global__ void zero_kernel(float4* __restrict__ z) {
  int i = blockIdx.x * blockDim.x + threadIdx.x;
  if (i < ZQUADS) z[i] = make_float4(0.f, 0.f, 0.f, 0.f);
}

// ---------- K2: init (4) ∪ emask (118) ∪ bucket (704) ----------

#define IB_INIT 4
#define IB_EMASK ((E_ + 255) / 256)
#define IB_BUCKET ((E_ * A_ + 255) / 256)
#define IB_BLOCKS (IB_INIT + IB_EMASK + IB_BUCKET)

__global__ __launch_bounds__(256) void init_bucket_kernel(
    const int* __restrict__ r_idx, const int* __restrict__ ents,
    const int* __restrict__ arity, const float* __restrict__ pos_table,
    const float* __restrict__ query_emb, const int* __restrict__ edge_list,
    int* __restrict__ seednode, float* __restrict__ seedvec,
    int* __restrict__ dirtyA, int* __restrict__ dirty_n, int* __restrict__ meta,
    int* __restrict__ deg, int* __restrict__ bucket, int* __restrict__ emask,
    int* __restrict__ nlist, int* __restrict__ cflag, int* __restrict__ ctrs) {
  __shared__ int diff[A_];
  int bid = blockIdx.x, t = threadIdx.x;
  if (bid < IB_INIT) {
    int b = bid;
    if (t < A_) diff[t] = 0;
    __syncthreads();
#pragma unroll
    for (int a = 0; a < A_; ++a) {
      int v0 = ents[(b * C_) * A_ + a];
      int dd = 0;
      for (int c = t; c < C_; c += 256) dd |= (ents[(b * C_ + c) * A_ + a] != v0);
      if (dd) diff[a] = 1;
    }
    __syncthreads();
    int ps = 0;
    for (int a = A_ - 1; a >= 0; --a) if (diff[a]) ps = a;
    int qr = r_idx[b * C_];
    if (t == 0) { meta[b] = ps; meta[B_ + b] = qr; }
    for (int c = t; c < C_; c += 256) {
      int n = ents[(b * C_ + c) * A_ + ps];
      cflag[n] = 1;
    }
    int ar = arity[b * C_];
    int lane = t & 63;
    for (int a = (t >> 6); a < A_; a += 4) {
      int slot = b * A_ + a;
      if (a < ar && a != ps) {
        int n = ents[(b * C_) * A_ + a];
        seedvec[slot * D_ + lane] = query_emb[qr * D_ + lane] + pos_table[(a + 1) * D_ + lane];
        if (lane == 0) {
          seednode[slot] = n;
          atomicOr(&dirtyA[n], 1 << b);
          int old = atomicOr(&dirty_n[n], 1 << b);
          if (old == 0) {
            int s3 = atomicAdd(&ctrs[2], 1);
            if (s3 < NLIST_CAP) nlist[s3] = n;
          }
        }
      } else {
        if (lane == 0) seednode[slot] = 0;
      }
    }
  } else if (bid < IB_INIT + IB_EMASK) {
    int e = (bid - IB_INIT) * 256 + t;
    if (e < E_) {
      int msk = 0;
#pragma unroll
      for (int a = 0; a < A_; ++a)
        if (edge_list[e * A_ + a]) msk |= 1 << a;
      emask[e] = msk;
    }
  } else {
    int i = (bid - IB_INIT - IB_EMASK) * 256 + t;
    if (i < E_ * A_) {
      int n = edge_list[i];
      if (n) {
        int slot = atomicAdd(&deg[n], 1);
        if (slot < DCAP) bucket[n * DCAP + slot] = i;
      }
    }
  }
}

// ---------- K3: eps (32 blocks, first) ∪ mainL0 (1251 blocks, 512 threads, 16-node tiles) ----------

#define MAIN_BLOCKS ((N_ + 15) / 16)   // 1251

__global__ __launch_bounds__(512) void main_eps_kernel(
    const int* __restrict__ deg, const int* __restrict__ bucket,
    const int* __restrict__ edge_list, const int* __restrict__ rel_list,
    const int* __restrict__ emask,
    const float* __restrict__ pos_table, const float* __restrict__ rel_emb_l,
    float* __restrict__ H1,
    const float* __restrict__ Wa, const float* __restrict__ bl_,
    const float* __restrict__ g_, const float* __restrict__ be_,
    const int* __restrict__ dirtyA, int* __restrict__ dirty_n,
    const int* __restrict__ seednode, const float* __restrict__ seedvec,
    float* __restrict__ Scorr, unsigned short* __restrict__ emap,
    int* __restrict__ eflag, int* __restrict__ nlist,
    int* __restrict__ ctrs) {
  __shared__ float A_lds[16 * 68];
  __shared__ float B_lds[64 * 64];
  int t = threadIdx.x;
  int wv = t >> 6, l = t & 63;

  float pv0 = pos_table[1 * D_ + l], pv1 = pos_table[2 * D_ + l];
  float pv2 = pos_table[3 * D_ + l], pv3 = pos_table[4 * D_ + l];
  float pv4 = pos_table[5 * D_ + l], pv5 = pos_table[6 * D_ + l];

  if (blockIdx.x < EPSB) {
    // ----- eps: wave claims dirty edge from seed buckets, then processes it -----
    int gw = blockIdx.x * 8 + wv;
    const int NW = EPSB * 8;
    for (int idx = gw; idx < B_ * A_ * DCAP; idx += NW) {
      int slot = idx / DCAP, p = idx - slot * DCAP;
      int n = seednode[slot];
      if (!n) continue;
      int dgn = deg[n]; dgn = (dgn > DCAP) ? DCAP : dgn;
      if (p >= dgn) continue;
      int e = bucket[n * DCAP + p] / 6;
      int claimed = 0;
      if (l == 0) claimed = (atomicOr(&eflag[e], 1) == 0);
      claimed = __shfl(claimed, 0);
      if (!claimed) continue;
      int mem[A_];
      int m = 0;
#pragma unroll
      for (int a = 0; a < A_; ++a) {
        mem[a] = edge_list[e * A_ + a];
        if (mem[a]) m |= dirtyA[mem[a]];
      }
#pragma unroll
      for (int a = 0; a < A_; ++a) {
        if (l == a && mem[a]) {
          int old = atomicOr(&dirty_n[mem[a]], m);
          if (old == 0) {
            int s3 = atomicAdd(&ctrs[2], 1);
            if (s3 < NLIST_CAP) nlist[s3] = mem[a];
          }
        }
      }
      float rel = rel_emb_l[rel_list[e] * D_ + l];
#pragma unroll
      for (int b = 0; b < B_; ++b) {
        if ((m >> b) & 1) {
          float s = 0.f;
#pragma unroll
          for (int a = 0; a < A_; ++a) {
            if (mem[a]) {
#pragma unroll
              for (int j = 0; j < A_; ++j) {
                int sl = b * A_ + j;
                if (seednode[sl] == mem[a]) s += seedvec[sl * D_ + l];
              }
            }
          }
          int slt = 0;
          if (l == 0) slt = atomicAdd(&ctrs[1], 1);
          slt = __shfl(slt, 0);
          if (slt < SC_CAP) {
            Scorr[slt * D_ + l] = rel * s;
            if (l == 0) emap[e * B_ + b] = (unsigned short)(slt + 1);
          }
        }
      }
    }
    return;
  }

  // ----- mainL0 (16-node tile, 8 waves, 2 nodes/wave) -----
  int m0 = (blockIdx.x - EPSB) * 16;

#pragma unroll
  for (int it = 0; it < 2; ++it) {
    int idx = t + 512 * it;
    reinterpret_cast<float4*>(B_lds)[idx] = reinterpret_cast<const float4*>(Wa)[idx];
  }

  for (int q = 0; q < 2; ++q) {
    int li = wv * 2 + q;
    int n = m0 + li;
    float aggv = 0.f;
    if (n < N_) {
      int dg = __builtin_amdgcn_readfirstlane(deg[n]);
      dg = (dg > DCAP) ? DCAP : dg;
      int base = n * DCAP;
      for (int p = 0; p < dg; p += 8) {
        int cnt = dg - p;
        int4 bq0 = *reinterpret_cast<const int4*>(&bucket[base + p]);
        int4 bq1 = *reinterpret_cast<const int4*>(&bucket[base + p + 4]);
        int idx8[8];
        idx8[0] = (0 < cnt) ? bq0.x : -1;
        idx8[1] = (1 < cnt) ? bq0.y : -1;
        idx8[2] = (2 < cnt) ? bq0.z : -1;
        idx8[3] = (3 < cnt) ? bq0.w : -1;
        idx8[4] = (4 < cnt) ? bq1.x : -1;
        idx8[5] = (5 < cnt) ? bq1.y : -1;
        idx8[6] = (6 < cnt) ? bq1.z : -1;
        idx8[7] = (7 < cnt) ? bq1.w : -1;
#pragma unroll
        for (int u = 0; u < 8; ++u) {
          if (idx8[u] >= 0) {
            int e = idx8[u] / 6, a = idx8[u] - e * 6;
            int msk = emask[e];
            float rel = rel_emb_l[rel_list[e] * D_ + l];
            float possum = 0.f;
            possum += (msk & 1) ? pv0 : 0.f;
            possum += (msk & 2) ? pv1 : 0.f;
            possum += (msk & 4) ? pv2 : 0.f;
            possum += (msk & 8) ? pv3 : 0.f;
            possum += (msk & 16) ? pv4 : 0.f;
            possum += (msk & 32) ? pv5 : 0.f;
            float pa = sel6(pv0, pv1, pv2, pv3, pv4, pv5, a);
            aggv = fmaf(rel, possum - pa, aggv);
          }
        }
      }
    }
    A_lds[li * 68 + l] = aggv;
  }
  __syncthreads();

  // GEMM 16x64: thread -> row = t>>5, cols (t&31)*2
  int row = t >> 5, c2 = (t & 31) * 2;
  float acc0 = bl_[c2], acc1 = bl_[c2 + 1];
#pragma unroll 8
  for (int k = 0; k < 64; ++k) {
    float2 b2v = *reinterpret_cast<const float2*>(&B_lds[k * 64 + c2]);
    float a = A_lds[row * 68 + k];
    acc0 = fmaf(a, b2v.x, acc0);
    acc1 = fmaf(a, b2v.y, acc1);
  }
  __syncthreads();
  *reinterpret_cast<float2*>(&A_lds[row * 68 + c2]) = make_float2(acc0, acc1);
  __syncthreads();

  float g = g_[l], be = be_[l];
#pragma unroll
  for (int rr = 0; rr < 2; ++rr) {
    int r = wv * 2 + rr;
    int n = m0 + r;
    float x = A_lds[r * 68 + l];
    float mu = wave_sum(x) * (1.f / 64.f);
    float dx = x - mu;
    float var = wave_sum(dx * dx) * (1.f / 64.f);
    float y = dx * rsqrtf(var + 1e-5f) * g + be;
    if (n < N_) H1[n * D_ + l] = fmaxf(y, 0.f);
  }
}

// ---------- K4: corr (64 blocks, nlist-driven) ∪ SB1/edirty build (7500 blocks, cflag-filtered) ----------

#define CORRB 64
#define SB1_BLOCKS ((E_ + 3) / 4)   // 7500

__global__ __launch_bounds__(256) void corr_sb1_kernel(
    const int* __restrict__ deg, const int* __restrict__ bucket,
    const int* __restrict__ edge_list, const int* __restrict__ rel_list,
    const int* __restrict__ emask,
    const float* __restrict__ pos_table,
    const float* __restrict__ rel0, const float* __restrict__ rel1,
    const float* __restrict__ Scorr, const unsigned short* __restrict__ emap,
    const int* __restrict__ dirty_n,
    const int* __restrict__ seednode, const float* __restrict__ seedvec,
    const float* __restrict__ H1,
    int* __restrict__ cmap, float* __restrict__ Hcorr,
    float* __restrict__ SB1, int* __restrict__ edirty,
    const int* __restrict__ nlist, const int* __restrict__ cflag,
    const float* __restrict__ Wa, const float* __restrict__ Ws,
    const float* __restrict__ bl_, const float* __restrict__ g_,
    const float* __restrict__ be_, int* __restrict__ ctrs) {
  int t = threadIdx.x;
  int wv = t >> 6, lane = t & 63;

  float pv0 = pos_table[1 * D_ + lane], pv1 = pos_table[2 * D_ + lane];
  float pv2 = pos_table[3 * D_ + lane], pv3 = pos_table[4 * D_ + lane];
  float pv4 = pos_table[5 * D_ + lane], pv5 = pos_table[6 * D_ + lane];

  if (blockIdx.x >= CORRB) {
    // ----- sb1 (only for candidate-incident edges) -----
    int e = (blockIdx.x - CORRB) * 4 + wv;
    if (e >= E_) return;
    int mem[A_];
#pragma unroll
    for (int a = 0; a < A_; ++a) mem[a] = edge_list[e * A_ + a];
    int cf = 0;
#pragma unroll
    for (int a = 0; a < A_; ++a)
      if (mem[a]) cf |= cflag[mem[a]];
    if (!cf) return;
    int ed = 0;
    float s = 0.f;
#pragma unroll
    for (int a = 0; a < A_; ++a) {
      if (mem[a]) {
        ed |= dirty_n[mem[a]];
        float pa = sel6(pv0, pv1, pv2, pv3, pv4, pv5, a);
        s += H1[mem[a] * D_ + lane] + pa;
      }
    }
    float rel = rel1[rel_list[e] * D_ + lane];
    SB1[e * D_ + lane] = rel * s;
    if (lane == 0) edirty[e] = ed;
    return;
  }

  // ----- corr (nlist-driven grid-stride) -----
  __shared__ float WaL[64 * 64];
  __shared__ float WsL[64 * 64];
#pragma unroll
  for (int it = 0; it < 4; ++it) {
    int idx = t + 256 * it;
    reinterpret_cast<float4*>(WaL)[idx] = reinterpret_cast<const float4*>(Wa)[idx];
    reinterpret_cast<float4*>(WsL)[idx] = reinterpret_cast<const float4*>(Ws)[idx];
  }
  __syncthreads();

  int cntn = ctrs[2]; if (cntn > NLIST_CAP) cntn = NLIST_CAP;
  for (int i = blockIdx.x * 4 + wv; i < cntn; i += CORRB * 4) {
    int n = nlist[i];
    int m = dirty_n[n];
    int slot = 0;
    if (lane == 0) slot = atomicAdd(&ctrs[3], 1);
    slot = __shfl(slot, 0);
    if (lane == 0) cmap[n] = slot;

    float blv = bl_[lane], gv = g_[lane], bev = be_[lane];
    int dg = deg[n]; dg = (dg > DCAP) ? DCAP : dg;
    int base = n * DCAP;
    float ss0 = 0.f, ss1 = 0.f, ss2 = 0.f, ss3 = 0.f;
    float rs = 0.f, ps = 0.f;
    for (int p = 0; p < dg; ++p) {
      int ii = bucket[base + p];
      int e = ii / 6, a = ii - e * 6;
      int msk = emask[e];
      float rel = rel0[rel_list[e] * D_ + lane];
      float possum = 0.f;
      possum += (msk & 1) ? pv0 : 0.f;
      possum += (msk & 2) ? pv1 : 0.f;
      possum += (msk & 4) ? pv2 : 0.f;
      possum += (msk & 8) ? pv3 : 0.f;
      possum += (msk & 16) ? pv4 : 0.f;
      possum += (msk & 32) ? pv5 : 0.f;
      float base_v = rel * possum;
      rs += rel;
      ps = fmaf(rel, sel6(pv0, pv1, pv2, pv3, pv4, pv5, a), ps);
      if ((m >> 0) & 1) { int ei = emap[e * B_ + 0]; ss0 += base_v + (ei ? Scorr[(ei - 1) * D_ + lane] : 0.f); }
      if ((m >> 1) & 1) { int ei = emap[e * B_ + 1]; ss1 += base_v + (ei ? Scorr[(ei - 1) * D_ + lane] : 0.f); }
      if ((m >> 2) & 1) { int ei = emap[e * B_ + 2]; ss2 += base_v + (ei ? Scorr[(ei - 1) * D_ + lane] : 0.f); }
      if ((m >> 3) & 1) { int ei = emap[e * B_ + 3]; ss3 += base_v + (ei ? Scorr[(ei - 1) * D_ + lane] : 0.f); }
    }
#pragma unroll
    for (int b = 0; b < B_; ++b) {
      if ((m >> b) & 1) {
        float ssb = (b == 0) ? ss0 : (b == 1) ? ss1 : (b == 2) ? ss2 : ss3;
        float hv = 0.f;
#pragma unroll
        for (int j = 0; j < A_; ++j) {
          int sl = b * A_ + j;
          if (seednode[sl] == n) hv += seedvec[sl * D_ + lane];
        }
        float aggv = ssb - hv * rs - ps;
        float out0 = blv, out1 = 0.f;
#pragma unroll
        for (int k = 0; k < 64; k += 2) {
          out0 = fmaf(rlane(aggv, k), WaL[k * 64 + lane], out0);
          out0 = fmaf(rlane(hv, k), WsL[k * 64 + lane], out0);
          out1 = fmaf(rlane(aggv, k + 1), WaL[(k + 1) * 64 + lane], out1);
          out1 = fmaf(rlane(hv, k + 1), WsL[(k + 1) * 64 + lane], out1);
        }
        float o = out0 + out1;
        float mu = wave_sum(o) * (1.f / 64.f);
        float dx = o - mu;
        float var = wave_sum(dx * dx) * (1.f / 64.f);
        float y = dx * rsqrtf(var + 1e-5f) * gv + bev;
        Hcorr[(slot * B_ + b) * D_ + lane] = fmaxf(y, 0.f) + hv;
      }
    }
  }
}

// ---------- K5: layer-2 at candidates via SB1, fused scoring ----------

__global__ __launch_bounds__(256) void cand_kernel(
    const int* __restrict__ ents, const int* __restrict__ meta,
    const int* __restrict__ deg, const int* __restrict__ bucket,
    const int* __restrict__ edge_list, const int* __restrict__ rel_list,
    const float* __restrict__ pos_table, const float* __restrict__ rel_emb_l,
    const float* __restrict__ H1, const float* __restrict__ Hcorr,
    const int* __restrict__ cmap, const int* __restrict__ dirty_n,
    const float* __restrict__ SB1, const int* __restrict__ edirty,
    const float* __restrict__ query_emb,
    const float* __restrict__ Wa, const float* __restrict__ Ws,
    const float* __restrict__ bl_, const float* __restrict__ g_,
    const float* __restrict__ be_,
    const float* __restrict__ W1, const float* __restrict__ b1,
    const float* __restrict__ W2, const float* __restrict__ b2,
    float* __restrict__ out) {
  __shared__ float WaL[64 * 64];
  __shared__ float WsL[64 * 64];
  int t = threadIdx.x;
#pragma unroll
  for (int it = 0; it < 4; ++it) {
    int idx = t + 256 * it;
    reinterpret_cast<float4*>(WaL)[idx] = reinterpret_cast<const float4*>(Wa)[idx];
    reinterpret_cast<float4*>(WsL)[idx] = reinterpret_cast<const float4*>(Ws)[idx];
  }
  __syncthreads();
  int w = blockIdx.x * 4 + (t >> 6);
  int lane = t & 63;
  if (w >= B_ * C_) return;
  int b = w / C_;
  int c = w - b * C_;
  int psn = meta[b];
  int qr = meta[B_ + b];
  int n = ents[(b * C_ + c) * A_ + psn];

  float pv0 = pos_table[1 * D_ + lane], pv1 = pos_table[2 * D_ + lane];
  float pv2 = pos_table[3 * D_ + lane], pv3 = pos_table[4 * D_ + lane];
  float pv4 = pos_table[5 * D_ + lane], pv5 = pos_table[6 * D_ + lane];

  float h1v = H1[n * D_ + lane];
  if ((dirty_n[n] >> b) & 1) h1v = Hcorr[(cmap[n] * B_ + b) * D_ + lane];

  int dg = __builtin_amdgcn_readfirstlane(deg[n]);
  dg = (dg > DCAP) ? DCAP : dg;
  int base = n * DCAP;
  float ss = 0.f, rs = 0.f, ps = 0.f;
  for (int p = 0; p < dg; ++p) {
    int ii = bucket[base + p];
    int e = ii / 6, a = ii - e * 6;
    float sb = SB1[e * D_ + lane];
    float rel = rel_emb_l[rel_list[e] * D_ + lane];
    int ed = edirty[e];
    if ((ed >> b) & 1) {
      float sdelta = 0.f;
#pragma unroll
      for (int a2 = 0; a2 < A_; ++a2) {
        int m2 = edge_list[e * A_ + a2];
        if (m2 && ((dirty_n[m2] >> b) & 1))
          sdelta += Hcorr[(cmap[m2] * B_ + b) * D_ + lane] - H1[m2 * D_ + lane];
      }
      sb = fmaf(rel, sdelta, sb);
    }
    ss += sb;
    rs += rel;
    ps = fmaf(rel, sel6(pv0, pv1, pv2, pv3, pv4, pv5, a), ps);
  }
  float aggv = ss - h1v * rs - ps;

  float out0 = bl_[lane], out1 = 0.f;
#pragma unroll
  for (int k = 0; k < 64; k += 2) {
    out0 = fmaf(rlane(aggv, k), WaL[k * 64 + lane], out0);
    out0 = fmaf(rlane(h1v, k), WsL[k * 64 + lane], out0);
    out1 = fmaf(rlane(aggv, k + 1), WaL[(k + 1) * 64 + lane], out1);
    out1 = fmaf(rlane(h1v, k + 1), WsL[(k + 1) * 64 + lane], out1);
  }
  float outv = out0 + out1;
  float mu = wave_sum(outv) * (1.f / 64.f);
  float dx = outv - mu;
  float var = wave_sum(dx * dx) * (1.f / 64.f);
  float y = dx * rsqrtf(var + 1e-5f) * g_[lane] + be_[lane];
  float h2v = fmaxf(y, 0.f) + h1v;

  float qv = query_emb[qr * D_ + lane];
  float h0a = b1[lane], h0b = 0.f;
  float h1a = b1[D_ + lane], h1b = 0.f;
#pragma unroll
  for (int k = 0; k < 64; k += 2) {
    float f0 = rlane(h2v, k), f1 = rlane(h2v, k + 1);
    h0a = fmaf(f0, W1[k * FEAT_ + lane], h0a);
    h1a = fmaf(f0, W1[k * FEAT_ + D_ + lane], h1a);
    h0b = fmaf(f1, W1[(k + 1) * FEAT_ + lane], h0b);
    h1b = fmaf(f1, W1[(k + 1) * FEAT_ + D_ + lane], h1b);
  }
#pragma unroll
  for (int k = 0; k < 64; k += 2) {
    float q0 = rlane(qv, k), q1 = rlane(qv, k + 1);
    h0a = fmaf(q0, W1[(D_ + k) * FEAT_ + lane], h0a);
    h1a = fmaf(q0, W1[(D_ + k) * FEAT_ + D_ + lane], h1a);
    h0b = fmaf(q1, W1[(D_ + k + 1) * FEAT_ + lane], h0b);
    h1b = fmaf(q1, W1[(D_ + k + 1) * FEAT_ + D_ + lane], h1b);
  }
  float hid0 = h0a + h0b, hid1 = h1a + h1b;
  float accs = fmaxf(hid0, 0.f) * W2[lane] + fmaxf(hid1, 0.f) * W2[D_ + lane];
  accs = wave_sum(accs);
  if (lane == 0) out[w] = accs + b2[0];
}

// ---------- launch ----------

extern "C" void kernel_launch(void* const* d_in, const int* in_sizes, int n_in,
                              void* d_out, int out_size, void* d_ws, size_t ws_size,
                              hipStream_t stream) {
  const int* r_idx = (const int*)d_in[0];
  const int* ents = (const int*)d_in[1];
  const int* arity = (const int*)d_in[2];
  const int* edge_list = (const int*)d_in[3];
  const int* rel_list = (const int*)d_in[4];
  const float* pos_table = (const float*)d_in[5];
  const float* query_emb = (const float*)d_in[6];
  const float* rel_emb = (const float*)d_in[7];
  const float* W_agg = (const float*)d_in[8];
  const float* W_self = (const float*)d_in[9];
  const float* b_lin = (const float*)d_in[10];
  const float* ln_g = (const float*)d_in[11];
  const float* ln_b = (const float*)d_in[12];
  const float* W1 = (const float*)d_in[13];
  const float* b1 = (const float*)d_in[14];
  const float* W2 = (const float*)d_in[15];
  const float* b2 = (const float*)d_in[16];
  float* out = (float*)d_out;

  char* ws = (char*)d_ws;
  float* H1      = (float*)(ws + 0);           //  5,120,256
  float* Hcorr   = (float*)(ws + 5120512);     // 20,481,024
  float* Scorr   = (float*)(ws + 25601536);    //  2,097,152
  int* cmap      = (int*)(ws + 27698688);      //     80,004
  int* seednode  = (int*)(ws + 27778816);      //         96
  float* seedvec = (float*)(ws + 27778912);    //      6,144
  int* meta      = (int*)(ws + 27785056);      //         32
  int* emask     = (int*)(ws + 27785216);      //    120,000
  int* bucket    = (int*)(ws + 27905216);      //  2,560,256
  int* nlist     = (int*)(ws + 33041856);      //     65,536
  float* SB1     = (float*)(ws + 33107392);    //  7,680,000
  int* edirty    = (int*)(ws + 40787392);      //    120,000
  const size_t Z = 40907392;  // 16-aligned zero region
  int* deg       = (int*)(ws + Z);                        //  80,016
  int* dirtyA    = (int*)(ws + Z + 80016);                //  80,016
  int* dirty_n   = (int*)(ws + Z + 160032);               //  80,016
  int* ctrs      = (int*)(ws + Z + 240048);               //      64
  int* eflag     = (int*)(ws + Z + 240112);               // 120,000
  unsigned short* emap = (unsigned short*)(ws + Z + 360112);  // 240,016
  int* cflag     = (int*)(ws + Z + 600128);               //  80,016
  const size_t ZBYTES = 680144;  // = ZQUADS*16
  if (ws_size < Z + ZBYTES) return;  // insufficient scratch; output stays poisoned

  const float* rel0 = rel_emb;
  const float* rel1 = rel_emb + R_ * D_;

  zero_kernel<<<(ZQUADS + 255) / 256, 256, 0, stream>>>((float4*)(ws + Z));

  init_bucket_kernel<<<IB_BLOCKS, 256, 0, stream>>>(
      r_idx, ents, arity, pos_table, query_emb, edge_list,
      seednode, seedvec, dirtyA, dirty_n, meta, deg, bucket, emask,
      nlist, cflag, ctrs);

  main_eps_kernel<<<EPSB + MAIN_BLOCKS, 512, 0, stream>>>(
      deg, bucket, edge_list, rel_list, emask, pos_table, rel0, H1,
      W_agg, b_lin, ln_g, ln_b,
      dirtyA, dirty_n, seednode, seedvec, Scorr, emap, eflag, nlist, ctrs);

  corr_sb1_kernel<<<CORRB + SB1_BLOCKS, 256, 0, stream>>>(
      deg, bucket, edge_list, rel_list, emask, pos_table, rel0, rel1,
      Scorr, emap, dirty_n, seednode, seedvec, H1,
      cmap, Hcorr, SB1, edirty, nlist, cflag,
      W_agg, W_self, b_lin, ln_g, ln_b, ctrs);

  cand_kernel<<<(B_ * C_ + 3) / 4, 256, 0, stream>>>(
      ents, meta, deg, bucket, edge_list, rel_list, pos_table, rel1,
      H1, Hcorr, cmap, dirty_n, SB1, edirty, query_emb,
      W_agg + D_ * D_, W_self + D_ * D_, b_lin + D_, ln_g + D_, ln_b + D_,
      W1, b1, W2, b2, out);

  (void)in_sizes; (void)n_in; (void)out_size;
}

// Round 17
// 98.157 us; speedup vs baseline: 1.0292x; 1.0292x over previous
//
#include <hip/hip_runtime.h>

#define D_ 64
#define R_ 50
#define N_ 20001
#define A_ 6
#define E_ 30000
#define B_ 4
#define C_ 500
#define FEAT_ 128
#define SC_CAP 8192
#define DCAP 32
#define NLIST_CAP 16384
#define EPSB 64

__device__ __forceinline__ float rlane(float v, int k) {
  return __builtin_bit_cast(float, __builtin_amdgcn_readlane(__builtin_bit_cast(int, v), k));
}
__device__ __forceinline__ float wave_sum(float v) {
#pragma unroll
  for (int off = 32; off; off >>= 1) v += __shfl_xor(v, off);
  return v;
}
__device__ __forceinline__ float sel6(float p0, float p1, float p2, float p3,
                                      float p4, float p5, int a) {
  float r = p0;
  r = (a == 1) ? p1 : r; r = (a == 2) ? p2 : r; r = (a == 3) ? p3 : r;
  r = (a == 4) ? p4 : r; r = (a == 5) ? p5 : r;
  return r;
}

// ---------- K1: zero scratch (deg/dirtyA/dirty_n/ctrs/eflag/emap/cflag) ----------

#define ZQUADS 42509  // 680144 bytes / 16

__global__ void zero_kernel(float4* __restrict__ z) {
  int i = blockIdx.x * blockDim.x + threadIdx.x;
  if (i < ZQUADS) z[i] = make_float4(0.f, 0.f, 0.f, 0.f);
}

// ---------- K2: init (4) ∪ emask (118) ∪ bucket (704) ----------

#define IB_INIT 4
#define IB_EMASK ((E_ + 255) / 256)
#define IB_BUCKET ((E_ * A_ + 255) / 256)
#define IB_BLOCKS (IB_INIT + IB_EMASK + IB_BUCKET)

__global__ __launch_bounds__(256) void init_bucket_kernel(
    const int* __restrict__ r_idx, const int* __restrict__ ents,
    const int* __restrict__ arity, const float* __restrict__ pos_table,
    const float* __restrict__ query_emb, const int* __restrict__ edge_list,
    int* __restrict__ seednode, float* __restrict__ seedvec,
    int* __restrict__ dirtyA, int* __restrict__ dirty_n, int* __restrict__ meta,
    int* __restrict__ deg, int* __restrict__ bucket, int* __restrict__ emask,
    int* __restrict__ nlist, int* __restrict__ cflag, int* __restrict__ ctrs) {
  __shared__ int diff[A_];
  int bid = blockIdx.x, t = threadIdx.x;
  if (bid < IB_INIT) {
    int b = bid;
    if (t < A_) diff[t] = 0;
    __syncthreads();
#pragma unroll
    for (int a = 0; a < A_; ++a) {
      int v0 = ents[(b * C_) * A_ + a];
      int dd = 0;
      for (int c = t; c < C_; c += 256) dd |= (ents[(b * C_ + c) * A_ + a] != v0);
      if (dd) diff[a] = 1;
    }
    __syncthreads();
    int ps = 0;
    for (int a = A_ - 1; a >= 0; --a) if (diff[a]) ps = a;
    int qr = r_idx[b * C_];
    if (t == 0) { meta[b] = ps; meta[B_ + b] = qr; }
    // mark candidate nodes for batch b (plain stores, races benign)
    for (int c = t; c < C_; c += 256) {
      int n = ents[(b * C_ + c) * A_ + ps];
      cflag[n] = 1;
    }
    int ar = arity[b * C_];
    int lane = t & 63;
    for (int a = (t >> 6); a < A_; a += 4) {
      int slot = b * A_ + a;
      if (a < ar && a != ps) {
        int n = ents[(b * C_) * A_ + a];
        seedvec[slot * D_ + lane] = query_emb[qr * D_ + lane] + pos_table[(a + 1) * D_ + lane];
        if (lane == 0) {
          seednode[slot] = n;
          atomicOr(&dirtyA[n], 1 << b);
          int old = atomicOr(&dirty_n[n], 1 << b);
          if (old == 0) {
            int s3 = atomicAdd(&ctrs[2], 1);
            if (s3 < NLIST_CAP) nlist[s3] = n;
          }
        }
      } else {
        if (lane == 0) seednode[slot] = 0;
      }
    }
  } else if (bid < IB_INIT + IB_EMASK) {
    int e = (bid - IB_INIT) * 256 + t;
    if (e < E_) {
      int msk = 0;
#pragma unroll
      for (int a = 0; a < A_; ++a)
        if (edge_list[e * A_ + a]) msk |= 1 << a;
      emask[e] = msk;
    }
  } else {
    int i = (bid - IB_INIT - IB_EMASK) * 256 + t;
    if (i < E_ * A_) {
      int n = edge_list[i];
      if (n) {
        int slot = atomicAdd(&deg[n], 1);
        if (slot < DCAP) bucket[n * DCAP + slot] = i;
      }
    }
  }
}

// ---------- K3: mainL0 (1251 blocks, 16-node tiles) ∪ eps (64 blocks, claim) ----------

#define MAIN_BLOCKS ((N_ + 15) / 16)   // 1251

__global__ __launch_bounds__(256) void main_eps_kernel(
    const int* __restrict__ deg, const int* __restrict__ bucket,
    const int* __restrict__ edge_list, const int* __restrict__ rel_list,
    const int* __restrict__ emask,
    const float* __restrict__ pos_table, const float* __restrict__ rel_emb_l,
    float* __restrict__ H1,
    const float* __restrict__ Wa, const float* __restrict__ bl_,
    const float* __restrict__ g_, const float* __restrict__ be_,
    const int* __restrict__ dirtyA, int* __restrict__ dirty_n,
    const int* __restrict__ seednode, const float* __restrict__ seedvec,
    float* __restrict__ Scorr, unsigned short* __restrict__ emap,
    int* __restrict__ eflag, int* __restrict__ nlist,
    int* __restrict__ ctrs) {
  __shared__ float A_lds[16 * 68];
  __shared__ float B_lds[64 * 64];
  int t = threadIdx.x;
  int wv = t >> 6, l = t & 63;

  float pv0 = pos_table[1 * D_ + l], pv1 = pos_table[2 * D_ + l];
  float pv2 = pos_table[3 * D_ + l], pv3 = pos_table[4 * D_ + l];
  float pv4 = pos_table[5 * D_ + l], pv5 = pos_table[6 * D_ + l];

  if (blockIdx.x >= MAIN_BLOCKS) {
    // ----- eps: wave claims dirty edge from seed buckets, then processes it -----
    int gw = (blockIdx.x - MAIN_BLOCKS) * 4 + wv;
    const int NW = EPSB * 4;
    for (int idx = gw; idx < B_ * A_ * DCAP; idx += NW) {
      int slot = idx / DCAP, p = idx - slot * DCAP;
      int n = seednode[slot];
      if (!n) continue;
      int dgn = deg[n]; dgn = (dgn > DCAP) ? DCAP : dgn;
      if (p >= dgn) continue;
      int e = bucket[n * DCAP + p] / 6;
      int claimed = 0;
      if (l == 0) claimed = (atomicOr(&eflag[e], 1) == 0);
      claimed = __shfl(claimed, 0);
      if (!claimed) continue;
      int mem[A_];
      int m = 0;
#pragma unroll
      for (int a = 0; a < A_; ++a) {
        mem[a] = edge_list[e * A_ + a];
        if (mem[a]) m |= dirtyA[mem[a]];
      }
#pragma unroll
      for (int a = 0; a < A_; ++a) {
        if (l == a && mem[a]) {
          int old = atomicOr(&dirty_n[mem[a]], m);
          if (old == 0) {
            int s3 = atomicAdd(&ctrs[2], 1);
            if (s3 < NLIST_CAP) nlist[s3] = mem[a];
          }
        }
      }
      float rel = rel_emb_l[rel_list[e] * D_ + l];
#pragma unroll
      for (int b = 0; b < B_; ++b) {
        if ((m >> b) & 1) {
          float s = 0.f;
#pragma unroll
          for (int a = 0; a < A_; ++a) {
            if (mem[a]) {
#pragma unroll
              for (int j = 0; j < A_; ++j) {
                int sl = b * A_ + j;
                if (seednode[sl] == mem[a]) s += seedvec[sl * D_ + l];
              }
            }
          }
          int slt = 0;
          if (l == 0) slt = atomicAdd(&ctrs[1], 1);
          slt = __shfl(slt, 0);
          if (slt < SC_CAP) {
            Scorr[slt * D_ + l] = rel * s;
            if (l == 0) emap[e * B_ + b] = (unsigned short)(slt + 1);
          }
        }
      }
    }
    return;
  }

  // ----- mainL0 (16-node tile) -----
  int m0 = blockIdx.x * 16;

#pragma unroll
  for (int it = 0; it < 4; ++it) {
    int idx = t + 256 * it;
    reinterpret_cast<float4*>(B_lds)[idx] = reinterpret_cast<const float4*>(Wa)[idx];
  }

  for (int q = 0; q < 4; ++q) {
    int li = wv * 4 + q;
    int n = m0 + li;
    float aggv = 0.f;
    if (n < N_) {
      int dg = __builtin_amdgcn_readfirstlane(deg[n]);
      dg = (dg > DCAP) ? DCAP : dg;
      int base = n * DCAP;
      for (int p = 0; p < dg; p += 8) {
        int cnt = dg - p;
        int4 bq0 = *reinterpret_cast<const int4*>(&bucket[base + p]);
        int4 bq1 = *reinterpret_cast<const int4*>(&bucket[base + p + 4]);
        int idx8[8];
        idx8[0] = (0 < cnt) ? bq0.x : -1;
        idx8[1] = (1 < cnt) ? bq0.y : -1;
        idx8[2] = (2 < cnt) ? bq0.z : -1;
        idx8[3] = (3 < cnt) ? bq0.w : -1;
        idx8[4] = (4 < cnt) ? bq1.x : -1;
        idx8[5] = (5 < cnt) ? bq1.y : -1;
        idx8[6] = (6 < cnt) ? bq1.z : -1;
        idx8[7] = (7 < cnt) ? bq1.w : -1;
#pragma unroll
        for (int u = 0; u < 8; ++u) {
          if (idx8[u] >= 0) {
            int e = idx8[u] / 6, a = idx8[u] - e * 6;
            int msk = emask[e];
            float rel = rel_emb_l[rel_list[e] * D_ + l];
            float possum = 0.f;
            possum += (msk & 1) ? pv0 : 0.f;
            possum += (msk & 2) ? pv1 : 0.f;
            possum += (msk & 4) ? pv2 : 0.f;
            possum += (msk & 8) ? pv3 : 0.f;
            possum += (msk & 16) ? pv4 : 0.f;
            possum += (msk & 32) ? pv5 : 0.f;
            float pa = sel6(pv0, pv1, pv2, pv3, pv4, pv5, a);
            aggv = fmaf(rel, possum - pa, aggv);
          }
        }
      }
    }
    A_lds[li * 68 + l] = aggv;
  }
  __syncthreads();

  int row = t >> 4, c4 = (t & 15) * 4;
  float4 bl4 = *reinterpret_cast<const float4*>(&bl_[c4]);
  float acc0 = bl4.x, acc1 = bl4.y, acc2 = bl4.z, acc3 = bl4.w;
#pragma unroll 8
  for (int k = 0; k < 64; ++k) {
    float4 b4 = *reinterpret_cast<const float4*>(&B_lds[k * 64 + c4]);
    float a = A_lds[row * 68 + k];
    acc0 = fmaf(a, b4.x, acc0); acc1 = fmaf(a, b4.y, acc1);
    acc2 = fmaf(a, b4.z, acc2); acc3 = fmaf(a, b4.w, acc3);
  }
  __syncthreads();
  *reinterpret_cast<float4*>(&A_lds[row * 68 + c4]) = make_float4(acc0, acc1, acc2, acc3);
  __syncthreads();

  float g = g_[l], be = be_[l];
#pragma unroll
  for (int rr = 0; rr < 4; ++rr) {
    int r = wv * 4 + rr;
    int n = m0 + r;
    float x = A_lds[r * 68 + l];
    float mu = wave_sum(x) * (1.f / 64.f);
    float dx = x - mu;
    float var = wave_sum(dx * dx) * (1.f / 64.f);
    float y = dx * rsqrtf(var + 1e-5f) * g + be;
    if (n < N_) H1[n * D_ + l] = fmaxf(y, 0.f);
  }
}

// ---------- K4: corr (64 blocks, nlist-driven) ∪ SB1/edirty build (7500 blocks, cflag-filtered) ----------

#define CORRB 64
#define SB1_BLOCKS ((E_ + 3) / 4)   // 7500

__global__ __launch_bounds__(256) void corr_sb1_kernel(
    const int* __restrict__ deg, const int* __restrict__ bucket,
    const int* __restrict__ edge_list, const int* __restrict__ rel_list,
    const int* __restrict__ emask,
    const float* __restrict__ pos_table,
    const float* __restrict__ rel0, const float* __restrict__ rel1,
    const float* __restrict__ Scorr, const unsigned short* __restrict__ emap,
    const int* __restrict__ dirty_n,
    const int* __restrict__ seednode, const float* __restrict__ seedvec,
    const float* __restrict__ H1,
    int* __restrict__ cmap, float* __restrict__ Hcorr,
    float* __restrict__ SB1, int* __restrict__ edirty,
    const int* __restrict__ nlist, const int* __restrict__ cflag,
    const float* __restrict__ Wa, const float* __restrict__ Ws,
    const float* __restrict__ bl_, const float* __restrict__ g_,
    const float* __restrict__ be_, int* __restrict__ ctrs) {
  int t = threadIdx.x;
  int wv = t >> 6, lane = t & 63;

  float pv0 = pos_table[1 * D_ + lane], pv1 = pos_table[2 * D_ + lane];
  float pv2 = pos_table[3 * D_ + lane], pv3 = pos_table[4 * D_ + lane];
  float pv4 = pos_table[5 * D_ + lane], pv5 = pos_table[6 * D_ + lane];

  if (blockIdx.x >= CORRB) {
    // ----- sb1 (only for candidate-incident edges) -----
    int e = (blockIdx.x - CORRB) * 4 + wv;
    if (e >= E_) return;
    int mem[A_];
#pragma unroll
    for (int a = 0; a < A_; ++a) mem[a] = edge_list[e * A_ + a];
    int cf = 0;
#pragma unroll
    for (int a = 0; a < A_; ++a)
      if (mem[a]) cf |= cflag[mem[a]];
    if (!cf) return;  // no candidate member: SB1/edirty never read for this edge
    int ed = 0;
    float s = 0.f;
#pragma unroll
    for (int a = 0; a < A_; ++a) {
      if (mem[a]) {
        ed |= dirty_n[mem[a]];
        float pa = sel6(pv0, pv1, pv2, pv3, pv4, pv5, a);
        s += H1[mem[a] * D_ + lane] + pa;
      }
    }
    float rel = rel1[rel_list[e] * D_ + lane];
    SB1[e * D_ + lane] = rel * s;
    if (lane == 0) edirty[e] = ed;
    return;
  }

  // ----- corr (nlist-driven grid-stride) -----
  __shared__ float WaL[64 * 64];
  __shared__ float WsL[64 * 64];
#pragma unroll
  for (int it = 0; it < 4; ++it) {
    int idx = t + 256 * it;
    reinterpret_cast<float4*>(WaL)[idx] = reinterpret_cast<const float4*>(Wa)[idx];
    reinterpret_cast<float4*>(WsL)[idx] = reinterpret_cast<const float4*>(Ws)[idx];
  }
  __syncthreads();

  int cntn = ctrs[2]; if (cntn > NLIST_CAP) cntn = NLIST_CAP;
  for (int i = blockIdx.x * 4 + wv; i < cntn; i += CORRB * 4) {
    int n = nlist[i];
    int m = dirty_n[n];
    int slot = 0;
    if (lane == 0) slot = atomicAdd(&ctrs[3], 1);
    slot = __shfl(slot, 0);
    if (lane == 0) cmap[n] = slot;

    float blv = bl_[lane], gv = g_[lane], bev = be_[lane];
    int dg = deg[n]; dg = (dg > DCAP) ? DCAP : dg;
    int base = n * DCAP;
    float ss0 = 0.f, ss1 = 0.f, ss2 = 0.f, ss3 = 0.f;
    float rs = 0.f, ps = 0.f;
    for (int p = 0; p < dg; ++p) {
      int ii = bucket[base + p];
      int e = ii / 6, a = ii - e * 6;
      int msk = emask[e];
      float rel = rel0[rel_list[e] * D_ + lane];
      float possum = 0.f;
      possum += (msk & 1) ? pv0 : 0.f;
      possum += (msk & 2) ? pv1 : 0.f;
      possum += (msk & 4) ? pv2 : 0.f;
      possum += (msk & 8) ? pv3 : 0.f;
      possum += (msk & 16) ? pv4 : 0.f;
      possum += (msk & 32) ? pv5 : 0.f;
      float base_v = rel * possum;
      rs += rel;
      ps = fmaf(rel, sel6(pv0, pv1, pv2, pv3, pv4, pv5, a), ps);
      if ((m >> 0) & 1) { int ei = emap[e * B_ + 0]; ss0 += base_v + (ei ? Scorr[(ei - 1) * D_ + lane] : 0.f); }
      if ((m >> 1) & 1) { int ei = emap[e * B_ + 1]; ss1 += base_v + (ei ? Scorr[(ei - 1) * D_ + lane] : 0.f); }
      if ((m >> 2) & 1) { int ei = emap[e * B_ + 2]; ss2 += base_v + (ei ? Scorr[(ei - 1) * D_ + lane] : 0.f); }
      if ((m >> 3) & 1) { int ei = emap[e * B_ + 3]; ss3 += base_v + (ei ? Scorr[(ei - 1) * D_ + lane] : 0.f); }
    }
#pragma unroll
    for (int b = 0; b < B_; ++b) {
      if ((m >> b) & 1) {
        float ssb = (b == 0) ? ss0 : (b == 1) ? ss1 : (b == 2) ? ss2 : ss3;
        float hv = 0.f;
#pragma unroll
        for (int j = 0; j < A_; ++j) {
          int sl = b * A_ + j;
          if (seednode[sl] == n) hv += seedvec[sl * D_ + lane];
        }
        float aggv = ssb - hv * rs - ps;
        float out0 = blv, out1 = 0.f;
#pragma unroll
        for (int k = 0; k < 64; k += 2) {
          out0 = fmaf(rlane(aggv, k), WaL[k * 64 + lane], out0);
          out0 = fmaf(rlane(hv, k), WsL[k * 64 + lane], out0);
          out1 = fmaf(rlane(aggv, k + 1), WaL[(k + 1) * 64 + lane], out1);
          out1 = fmaf(rlane(hv, k + 1), WsL[(k + 1) * 64 + lane], out1);
        }
        float o = out0 + out1;
        float mu = wave_sum(o) * (1.f / 64.f);
        float dx = o - mu;
        float var = wave_sum(dx * dx) * (1.f / 64.f);
        float y = dx * rsqrtf(var + 1e-5f) * gv + bev;
        Hcorr[(slot * B_ + b) * D_ + lane] = fmaxf(y, 0.f) + hv;
      }
    }
  }
}

// ---------- K5: layer-2 at candidates via SB1, fused scoring ----------

__global__ __launch_bounds__(256) void cand_kernel(
    const int* __restrict__ ents, const int* __restrict__ meta,
    const int* __restrict__ deg, const int* __restrict__ bucket,
    const int* __restrict__ edge_list, const int* __restrict__ rel_list,
    const float* __restrict__ pos_table, const float* __restrict__ rel_emb_l,
    const float* __restrict__ H1, const float* __restrict__ Hcorr,
    const int* __restrict__ cmap, const int* __restrict__ dirty_n,
    const float* __restrict__ SB1, const int* __restrict__ edirty,
    const float* __restrict__ query_emb,
    const float* __restrict__ Wa, const float* __restrict__ Ws,
    const float* __restrict__ bl_, const float* __restrict__ g_,
    const float* __restrict__ be_,
    const float* __restrict__ W1, const float* __restrict__ b1,
    const float* __restrict__ W2, const float* __restrict__ b2,
    float* __restrict__ out) {
  __shared__ float WaL[64 * 64];
  __shared__ float WsL[64 * 64];
  int t = threadIdx.x;
#pragma unroll
  for (int it = 0; it < 4; ++it) {
    int idx = t + 256 * it;
    reinterpret_cast<float4*>(WaL)[idx] = reinterpret_cast<const float4*>(Wa)[idx];
    reinterpret_cast<float4*>(WsL)[idx] = reinterpret_cast<const float4*>(Ws)[idx];
  }
  __syncthreads();
  int w = blockIdx.x * 4 + (t >> 6);
  int lane = t & 63;
  if (w >= B_ * C_) return;
  int b = w / C_;
  int c = w - b * C_;
  int psn = meta[b];
  int qr = meta[B_ + b];
  int n = ents[(b * C_ + c) * A_ + psn];

  float pv0 = pos_table[1 * D_ + lane], pv1 = pos_table[2 * D_ + lane];
  float pv2 = pos_table[3 * D_ + lane], pv3 = pos_table[4 * D_ + lane];
  float pv4 = pos_table[5 * D_ + lane], pv5 = pos_table[6 * D_ + lane];

  float h1v = H1[n * D_ + lane];
  if ((dirty_n[n] >> b) & 1) h1v = Hcorr[(cmap[n] * B_ + b) * D_ + lane];

  int dg = __builtin_amdgcn_readfirstlane(deg[n]);
  dg = (dg > DCAP) ? DCAP : dg;
  int base = n * DCAP;
  float ss = 0.f, rs = 0.f, ps = 0.f;
  for (int p = 0; p < dg; ++p) {
    int ii = bucket[base + p];
    int e = ii / 6, a = ii - e * 6;
    float sb = SB1[e * D_ + lane];
    float rel = rel_emb_l[rel_list[e] * D_ + lane];
    int ed = edirty[e];
    if ((ed >> b) & 1) {
      float sdelta = 0.f;
#pragma unroll
      for (int a2 = 0; a2 < A_; ++a2) {
        int m2 = edge_list[e * A_ + a2];
        if (m2 && ((dirty_n[m2] >> b) & 1))
          sdelta += Hcorr[(cmap[m2] * B_ + b) * D_ + lane] - H1[m2 * D_ + lane];
      }
      sb = fmaf(rel, sdelta, sb);
    }
    ss += sb;
    rs += rel;
    ps = fmaf(rel, sel6(pv0, pv1, pv2, pv3, pv4, pv5, a), ps);
  }
  float aggv = ss - h1v * rs - ps;

  float out0 = bl_[lane], out1 = 0.f;
#pragma unroll
  for (int k = 0; k < 64; k += 2) {
    out0 = fmaf(rlane(aggv, k), WaL[k * 64 + lane], out0);
    out0 = fmaf(rlane(h1v, k), WsL[k * 64 + lane], out0);
    out1 = fmaf(rlane(aggv, k + 1), WaL[(k + 1) * 64 + lane], out1);
    out1 = fmaf(rlane(h1v, k + 1), WsL[(k + 1) * 64 + lane], out1);
  }
  float outv = out0 + out1;
  float mu = wave_sum(outv) * (1.f / 64.f);
  float dx = outv - mu;
  float var = wave_sum(dx * dx) * (1.f / 64.f);
  float y = dx * rsqrtf(var + 1e-5f) * g_[lane] + be_[lane];
  float h2v = fmaxf(y, 0.f) + h1v;

  float qv = query_emb[qr * D_ + lane];
  float h0a = b1[lane], h0b = 0.f;
  float h1a = b1[D_ + lane], h1b = 0.f;
#pragma unroll
  for (int k = 0; k < 64; k += 2) {
    float f0 = rlane(h2v, k), f1 = rlane(h2v, k + 1);
    h0a = fmaf(f0, W1[k * FEAT_ + lane], h0a);
    h1a = fmaf(f0, W1[k * FEAT_ + D_ + lane], h1a);
    h0b = fmaf(f1, W1[(k + 1) * FEAT_ + lane], h0b);
    h1b = fmaf(f1, W1[(k + 1) * FEAT_ + D_ + lane], h1b);
  }
#pragma unroll
  for (int k = 0; k < 64; k += 2) {
    float q0 = rlane(qv, k), q1 = rlane(qv, k + 1);
    h0a = fmaf(q0, W1[(D_ + k) * FEAT_ + lane], h0a);
    h1a = fmaf(q0, W1[(D_ + k) * FEAT_ + D_ + lane], h1a);
    h0b = fmaf(q1, W1[(D_ + k + 1) * FEAT_ + lane], h0b);
    h1b = fmaf(q1, W1[(D_ + k + 1) * FEAT_ + D_ + lane], h1b);
  }
  float hid0 = h0a + h0b, hid1 = h1a + h1b;
  float accs = fmaxf(hid0, 0.f) * W2[lane] + fmaxf(hid1, 0.f) * W2[D_ + lane];
  accs = wave_sum(accs);
  if (lane == 0) out[w] = accs + b2[0];
}

// ---------- launch ----------

extern "C" void kernel_launch(void* const* d_in, const int* in_sizes, int n_in,
                              void* d_out, int out_size, void* d_ws, size_t ws_size,
                              hipStream_t stream) {
  const int* r_idx = (const int*)d_in[0];
  const int* ents = (const int*)d_in[1];
  const int* arity = (const int*)d_in[2];
  const int* edge_list = (const int*)d_in[3];
  const int* rel_list = (const int*)d_in[4];
  const float* pos_table = (const float*)d_in[5];
  const float* query_emb = (const float*)d_in[6];
  const float* rel_emb = (const float*)d_in[7];
  const float* W_agg = (const float*)d_in[8];
  const float* W_self = (const float*)d_in[9];
  const float* b_lin = (const float*)d_in[10];
  const float* ln_g = (const float*)d_in[11];
  const float* ln_b = (const float*)d_in[12];
  const float* W1 = (const float*)d_in[13];
  const float* b1 = (const float*)d_in[14];
  const float* W2 = (const float*)d_in[15];
  const float* b2 = (const float*)d_in[16];
  float* out = (float*)d_out;

  char* ws = (char*)d_ws;
  // layout (bytes)
  float* H1      = (float*)(ws + 0);           //  5,120,256
  float* Hcorr   = (float*)(ws + 5120512);     // 20,481,024
  float* Scorr   = (float*)(ws + 25601536);    //  2,097,152
  int* cmap      = (int*)(ws + 27698688);      //     80,004
  int* seednode  = (int*)(ws + 27778816);      //         96
  float* seedvec = (float*)(ws + 27778912);    //      6,144
  int* meta      = (int*)(ws + 27785056);      //         32
  int* emask     = (int*)(ws + 27785216);      //    120,000
  int* bucket    = (int*)(ws + 27905216);      //  2,560,256
  int* nlist     = (int*)(ws + 33041856);      //     65,536
  float* SB1     = (float*)(ws + 33107392);    //  7,680,000
  int* edirty    = (int*)(ws + 40787392);      //    120,000
  // contiguous zero region:
  const size_t Z = 40907392;  // 16-aligned
  int* deg       = (int*)(ws + Z);                        //  80,016
  int* dirtyA    = (int*)(ws + Z + 80016);                //  80,016
  int* dirty_n   = (int*)(ws + Z + 160032);               //  80,016
  int* ctrs      = (int*)(ws + Z + 240048);               //      64
  int* eflag     = (int*)(ws + Z + 240112);               // 120,000
  unsigned short* emap = (unsigned short*)(ws + Z + 360112);  // 240,016
  int* cflag     = (int*)(ws + Z + 600128);               //  80,016
  const size_t ZBYTES = 680144;  // = ZQUADS*16
  if (ws_size < Z + ZBYTES) return;  // insufficient scratch; output stays poisoned

  const float* rel0 = rel_emb;
  const float* rel1 = rel_emb + R_ * D_;

  zero_kernel<<<(ZQUADS + 255) / 256, 256, 0, stream>>>((float4*)(ws + Z));

  init_bucket_kernel<<<IB_BLOCKS, 256, 0, stream>>>(
      r_idx, ents, arity, pos_table, query_emb, edge_list,
      seednode, seedvec, dirtyA, dirty_n, meta, deg, bucket, emask,
      nlist, cflag, ctrs);

  main_eps_kernel<<<MAIN_BLOCKS + EPSB, 256, 0, stream>>>(
      deg, bucket, edge_list, rel_list, emask, pos_table, rel0, H1,
      W_agg, b_lin, ln_g, ln_b,
      dirtyA, dirty_n, seednode, seedvec, Scorr, emap, eflag, nlist, ctrs);

  corr_sb1_kernel<<<CORRB + SB1_BLOCKS, 256, 0, stream>>>(
      deg, bucket, edge_list, rel_list, emask, pos_table, rel0, rel1,
      Scorr, emap, dirty_n, seednode, seedvec, H1,
      cmap, Hcorr, SB1, edirty, nlist, cflag,
      W_agg, W_self, b_lin, ln_g, ln_b, ctrs);

  cand_kernel<<<(B_ * C_ + 3) / 4, 256, 0, stream>>>(
      ents, meta, deg, bucket, edge_list, rel_list, pos_table, rel1,
      H1, Hcorr, cmap, dirty_n, SB1, edirty, query_emb,
      W_agg + D_ * D_, W_self + D_ * D_, b_lin + D_, ln_g + D_, ln_b + D_,
      W1, b1, W2, b2, out);

  (void)in_sizes; (void)n_in; (void)out_size;
}